// Round 8
// baseline (210.319 us; speedup 1.0000x reference)
//
#include <hip/hip_runtime.h>
#include <hip/hip_bf16.h>
#include <stdint.h>

typedef __attribute__((ext_vector_type(4))) int i32x4;

#define K_DIM 4096
#define M_DIM 8192
#define N_DIM 4096

#define BM 256
#define BN 256
#define BKB 128                  // K-bytes (=128 i8) per K-tile
#define K_TILES (K_DIM / BKB)    // 32
#define GITERS (K_TILES / 2)     // 16 iterations, 2 K-tiles each

// ---------------------------------------------------------------- helpers
__device__ __forceinline__ void gload_lds16(const void* g, void* l) {
    __builtin_amdgcn_global_load_lds(
        (__attribute__((address_space(1))) void*)(void*)g,
        (__attribute__((address_space(3))) void*)(void*)l,
        16, 0, 0);
}

// ---------------------------------------------------------------- kernel 1: fused min/max partials + weight conv
// blocks 0..1023:  grid-stride min/max over x -> partials
// blocks 1024..2047: weight fp32 -> i8 + rowsum (4 rows/block, 1 wave/row)
__global__ void mmcw_kernel(const float* __restrict__ x, long n4,
                            float* __restrict__ partials,
                            const float* __restrict__ w,
                            signed char* __restrict__ Wq,
                            int* __restrict__ rowsum) {
    if (blockIdx.x < 1024) {
        const float4* x4 = (const float4*)x;
        float mn = 1e30f, mx = -1e30f;
        long stride = (long)1024 * blockDim.x;
        for (long i = (long)blockIdx.x * blockDim.x + threadIdx.x; i < n4; i += stride) {
            float4 v = x4[i];
            mn = fminf(mn, fminf(fminf(v.x, v.y), fminf(v.z, v.w)));
            mx = fmaxf(mx, fmaxf(fmaxf(v.x, v.y), fmaxf(v.z, v.w)));
        }
        #pragma unroll
        for (int off = 32; off; off >>= 1) {
            mn = fminf(mn, __shfl_down(mn, off));
            mx = fmaxf(mx, __shfl_down(mx, off));
        }
        __shared__ float smn[4], smx[4];
        int wid = threadIdx.x >> 6, lane = threadIdx.x & 63;
        if (lane == 0) { smn[wid] = mn; smx[wid] = mx; }
        __syncthreads();
        if (threadIdx.x == 0) {
            mn = fminf(fminf(smn[0], smn[1]), fminf(smn[2], smn[3]));
            mx = fmaxf(fmaxf(smx[0], smx[1]), fmaxf(smx[2], smx[3]));
            partials[blockIdx.x] = mn;
            partials[1024 + blockIdx.x] = mx;
        }
    } else {
        int row = (blockIdx.x - 1024) * 4 + (threadIdx.x >> 6);
        int lane = threadIdx.x & 63;
        const float4* src = (const float4*)(w + (long)row * K_DIM);  // 1024 float4/row
        uint4* dst = (uint4*)(Wq + (long)row * K_DIM);               // 256 uint4/row
        float s = 0.f;
        #pragma unroll
        for (int k = 0; k < 4; k++) {
            int u = k * 64 + lane;          // uint4 index 0..255
            unsigned wrd[4];
            #pragma unroll
            for (int j = 0; j < 4; j++) {
                float4 v = src[u * 4 + j];
                float e[4] = {v.x, v.y, v.z, v.w};
                unsigned word = 0;
                #pragma unroll
                for (int b = 0; b < 4; b++) {
                    int iv = (int)e[b];                  // exact: integer-valued fp32
                    s += e[b];
                    word |= ((unsigned)iv & 0xffu) << (8 * b);
                }
                wrd[j] = word;
            }
            uint4 o; o.x = wrd[0]; o.y = wrd[1]; o.z = wrd[2]; o.w = wrd[3];
            dst[u] = o;
        }
        #pragma unroll
        for (int off = 32; off; off >>= 1) s += __shfl_down(s, off);
        if (lane == 0) rowsum[row] = (int)s;             // exact: |sum| < 2^24
    }
}

// ---------------------------------------------------------------- kernel 2: finalize scalars + fold epilogue coeffs
__global__ void finalize_fold_kernel(const float* __restrict__ partials,
                                     const int* __restrict__ rowsum,
                                     const float* __restrict__ wscale,
                                     const float* __restrict__ bias,
                                     float* __restrict__ scal,
                                     float* __restrict__ outscale,
                                     float* __restrict__ bias2) {
    float mn = 1e30f, mx = -1e30f;
    for (int i = threadIdx.x; i < 1024; i += 256) {
        mn = fminf(mn, partials[i]);
        mx = fmaxf(mx, partials[1024 + i]);
    }
    #pragma unroll
    for (int off = 32; off; off >>= 1) {
        mn = fminf(mn, __shfl_down(mn, off));
        mx = fmaxf(mx, __shfl_down(mx, off));
    }
    __shared__ float smn[4], smx[4];
    __shared__ float s_scale, s_zp;
    int wid = threadIdx.x >> 6, lane = threadIdx.x & 63;
    if (lane == 0) { smn[wid] = mn; smx[wid] = mx; }
    __syncthreads();
    if (threadIdx.x == 0) {
        mn = fminf(fminf(smn[0], smn[1]), fminf(smn[2], smn[3]));
        mx = fmaxf(fmaxf(smx[0], smx[1]), fmaxf(smx[2], smx[3]));
        float scale = (mx - mn) / 255.0f;
        float zp = rintf(-128.0f - mn / scale);
        zp = fminf(fmaxf(zp, -128.0f), 127.0f);
        scal[0] = scale;
        scal[1] = zp;
        s_scale = scale; s_zp = zp;
    }
    __syncthreads();
    float scale = s_scale, zp = s_zp;
    for (int i = threadIdx.x; i < 4096; i += 256) {
        float os = scale * wscale[i];
        outscale[i] = os;
        bias2[i] = bias[i] - zp * (float)rowsum[i] * os;
    }
}

// ---------------------------------------------------------------- kernel 3: quantize x -> i8
__global__ void quantize_kernel(const float* __restrict__ x,
                                const float* __restrict__ scal,
                                uint4* __restrict__ q, long n16) {
    float scale = scal[0];
    float zp = scal[1];
    long stride = (long)gridDim.x * blockDim.x;
    for (long i = (long)blockIdx.x * blockDim.x + threadIdx.x; i < n16; i += stride) {
        const float4* xp = (const float4*)x + i * 4;
        unsigned wrd[4];
        #pragma unroll
        for (int w = 0; w < 4; w++) {
            float4 v = xp[w];
            float e[4] = {v.x, v.y, v.z, v.w};
            unsigned word = 0;
            #pragma unroll
            for (int j = 0; j < 4; j++) {
                float qf = rintf(e[j] / scale + zp);          // matches reference rounding
                qf = fminf(fmaxf(qf, -128.0f), 127.0f);
                int iq = (int)qf;
                word |= ((unsigned)iq & 0xffu) << (8 * j);
            }
            wrd[w] = word;
        }
        uint4 o; o.x = wrd[0]; o.y = wrd[1]; o.z = wrd[2]; o.w = wrd[3];
        q[i] = o;
    }
}

// ---------------------------------------------------------------- kernel 4: i8 GEMM, 8-phase, read-ahead pipelined
// Same stage/vmcnt/barrier skeleton as the verified round-5/7 kernel; the
// ds_reads are moved one phase ahead into 4 rotating register banks
// (aA,aB,b0,b1) so LDS-read latency/occupancy overlaps the MFMA clusters.
// vmcnt-dependent reads (P4: odd-half0, P8: next-even-half0) sit AFTER the
// mid-barrier that globalizes the per-wave vmcnt confirm. Prologue drains
// with vmcnt(0) (fixes latent it=0 under-confirmation; steady-state ledger
// identical). Compiler emits counted lgkmcnt at each consuming MFMA.
__global__ __launch_bounds__(512, 2) void gemm_kernel(
    const signed char* __restrict__ A,   // [8192][4096] i8 (q, zp NOT subtracted)
    const signed char* __restrict__ W,   // [4096][4096] i8
    const float* __restrict__ outscale,
    const float* __restrict__ bias2,
    float* __restrict__ C) {
    extern __shared__ char lds[];
    char* As = lds;            // 2 bufs x 32768 B (2 units x 128 rows x 128 B)
    char* Bs = lds + 65536;

    // XCD-aware swizzle (nwg = 512, divisible by 8)
    int nwg = gridDim.x;
    int cpx = nwg >> 3;
    int bid = blockIdx.x;
    int wg = (bid & 7) * cpx + (bid >> 3);
    int tm = wg >> 4;   // 32 M-tiles
    int tn = wg & 15;   // 16 N-tiles
    int m0 = tm * BM, n0 = tn * BN;

    int t = threadIdx.x;
    int wid = t >> 6, lane = t & 63;
    int wr = wid >> 2, wc = wid & 3;      // 2 x 4 wave grid
    int lr = lane & 15, lk = lane >> 4;
    int ksw0 = (lk ^ (lr & 7)) * 16;          // byte offset, khalf0 (k 0..63)
    int ksw1 = ((4 + lk) ^ (lr & 7)) * 16;    // khalf1 (k 64..127)

    // staging source geometry (byte units)
    int R0 = t >> 3;                              // 0..63
    int csw = ((t & 7) ^ ((t >> 3) & 7)) * 16;    // inverse-swizzled source col
    const signed char* aSrc = A + (long)(m0 + R0) * K_DIM + csw;
    const signed char* bSrc = W + (long)(n0 + ((R0 >> 5) << 6) + (R0 & 31)) * K_DIM + csw;
    int ldd = t * 16;                             // lds dest bytes

#define STAGE_A(BUF, UN, KT) do { \
    const signed char* _s = aSrc + (long)(UN) * 64 * K_DIM + (long)(KT) * BKB; \
    char* _d = As + (BUF) * 32768 + (UN) * 16384 + ldd; \
    gload_lds16(_s, _d); \
    gload_lds16(_s + (long)128 * K_DIM, _d + 8192); } while (0)

#define STAGE_B(BUF, UN, KT) do { \
    const signed char* _s = bSrc + (long)(UN) * 32 * K_DIM + (long)(KT) * BKB; \
    char* _d = Bs + (BUF) * 32768 + (UN) * 16384 + ldd; \
    gload_lds16(_s, _d); \
    gload_lds16(_s + (long)128 * K_DIM, _d + 8192); } while (0)

#define READ_A(BUF, MH, AR) do { \
    const char* _p = As + (BUF) * 32768 + (MH) * 16384 + (wr * 64 + lr) * 128; \
    _Pragma("unroll") \
    for (int _mm = 0; _mm < 4; ++_mm) { \
        AR[_mm * 2]     = *(const i32x4*)(_p + _mm * 2048 + ksw0); \
        AR[_mm * 2 + 1] = *(const i32x4*)(_p + _mm * 2048 + ksw1); } } while (0)

#define READ_B(BUF, NH, BR) do { \
    const char* _p = Bs + (BUF) * 32768 + (NH) * 16384 + (wc * 32 + lr) * 128; \
    _Pragma("unroll") \
    for (int _nn = 0; _nn < 2; ++_nn) { \
        BR[_nn * 2]     = *(const i32x4*)(_p + _nn * 2048 + ksw0); \
        BR[_nn * 2 + 1] = *(const i32x4*)(_p + _nn * 2048 + ksw1); } } while (0)

#define MFMA_QUAD(MH, NH, AR, BR) do { \
    _Pragma("unroll") \
    for (int _mm = 0; _mm < 4; ++_mm) \
    _Pragma("unroll") \
    for (int _nn = 0; _nn < 2; ++_nn) { \
        acc[(MH) * 4 + _mm][(NH) * 2 + _nn] = __builtin_amdgcn_mfma_i32_16x16x64_i8( \
            AR[_mm * 2], BR[_nn * 2], acc[(MH) * 4 + _mm][(NH) * 2 + _nn], 0, 0, 0); \
        acc[(MH) * 4 + _mm][(NH) * 2 + _nn] = __builtin_amdgcn_mfma_i32_16x16x64_i8( \
            AR[_mm * 2 + 1], BR[_nn * 2 + 1], acc[(MH) * 4 + _mm][(NH) * 2 + _nn], 0, 0, 0); } } while (0)

#define BAR()   asm volatile("s_barrier" ::: "memory")
#define VM6()   asm volatile("s_waitcnt vmcnt(6)" ::: "memory")
#define VM0()   asm volatile("s_waitcnt vmcnt(0)" ::: "memory")
#define PRIO1() __builtin_amdgcn_s_setprio(1)
#define PRIO0() __builtin_amdgcn_s_setprio(0)

    i32x4 acc[8][4];
    #pragma unroll
    for (int i = 0; i < 8; i++)
        #pragma unroll
        for (int j = 0; j < 4; j++)
            acc[i][j] = (i32x4){0, 0, 0, 0};

    i32x4 aA[8], aB[8], b0[4], b1[4];

    // ---- prologue: tile0 fully -> buf0, tile1 units u0A,u0B,u1B -> buf1
    STAGE_A(0, 0, 0); STAGE_B(0, 0, 0); STAGE_B(0, 1, 0); STAGE_A(0, 1, 0);
    STAGE_A(1, 0, 1); STAGE_B(1, 0, 1); STAGE_B(1, 1, 1);
    VM0();   // drain all: tile0 AND tile1 partials landed (globalized by BAR)
    BAR();
    READ_A(0, 0, aA);      // even A-half0
    READ_B(0, 0, b1);      // even B-half0

    for (int it = 0; it < GITERS; ++it) {
        int t1 = 2 * it + 1;
        int tn0 = 2 * it + 2, tn1 = 2 * it + 3;
        bool st = (it < GITERS - 1);

        // ---- P1: MFMA (0,0) even
        READ_B(0, 1, b0);              // even B-half1 (for P2/P3)
        STAGE_A(1, 1, t1);
        BAR();
        PRIO1(); MFMA_QUAD(0, 0, aA, b1); PRIO0();
        BAR();

        // ---- P2: (0,1) even
        READ_A(0, 1, aB);              // even A-half1 (for P3/P4)
        if (st) STAGE_A(0, 0, tn0);
        BAR();
        PRIO1(); MFMA_QUAD(0, 1, aA, b0); PRIO0();
        BAR();

        // ---- P3: (1,1) even
        if (st) STAGE_B(0, 0, tn0);
        BAR();
        PRIO1(); MFMA_QUAD(1, 1, aB, b0); PRIO0();
        BAR();

        // ---- P4: (1,0) even  [vmcnt point; odd-half0 reads after mid-BAR]
        if (st) { STAGE_B(0, 1, tn0); VM6(); } else { VM0(); }
        BAR();
        READ_A(1, 0, aA);              // odd A-half0 (for P5/P6)
        READ_B(1, 0, b0);              // odd B-half0 (for P5/P8)
        PRIO1(); MFMA_QUAD(1, 0, aB, b1); PRIO0();
        BAR();

        // ---- P5: (0,0) odd
        READ_B(1, 1, b1);              // odd B-half1 (for P6/P7)
        if (st) STAGE_A(0, 1, tn0);
        BAR();
        PRIO1(); MFMA_QUAD(0, 0, aA, b0); PRIO0();
        BAR();

        // ---- P6: (0,1) odd
        READ_A(1, 1, aB);              // odd A-half1 (for P7/P8)
        if (st) STAGE_A(1, 0, tn1);
        BAR();
        PRIO1(); MFMA_QUAD(0, 1, aA, b1); PRIO0();
        BAR();

        // ---- P7: (1,1) odd
        if (st) STAGE_B(1, 0, tn1);
        BAR();
        PRIO1(); MFMA_QUAD(1, 1, aB, b1); PRIO0();
        BAR();

        // ---- P8: (1,0) odd  [vmcnt point; next-even-half0 reads after mid-BAR]
        if (st) { STAGE_B(1, 1, tn1); VM6(); }
        BAR();
        if (st) {
            READ_A(0, 0, aA);          // next even A-half0 (for P1/P2)
            READ_B(0, 0, b1);          // next even B-half0 (for P1/P4)
        }
        PRIO1(); MFMA_QUAD(1, 0, aB, b0); PRIO0();
        BAR();
    }

    // ---- epilogue: C/D layout col = lane&15, row = (lane>>4)*4 + reg
    #pragma unroll
    for (int j = 0; j < 4; j++) {
        int col = n0 + wc * 64 + j * 16 + lr;
        float os = outscale[col];
        float bs = bias2[col];
        #pragma unroll
        for (int i = 0; i < 8; i++) {
            int rbase = m0 + wr * 128 + i * 16 + lk * 4;
            #pragma unroll
            for (int r = 0; r < 4; r++) {
                C[(long)(rbase + r) * N_DIM + col] = (float)acc[i][j][r] * os + bs;
            }
        }
    }
#undef STAGE_A
#undef STAGE_B
#undef READ_A
#undef READ_B
#undef MFMA_QUAD
}

// ---------------------------------------------------------------- launch
extern "C" void kernel_launch(void* const* d_in, const int* in_sizes, int n_in,
                              void* d_out, int out_size, void* d_ws, size_t ws_size,
                              hipStream_t stream) {
    const float* x      = (const float*)d_in[0];  // [4,2048,4096]
    const float* weight = (const float*)d_in[1];  // [4096,4096] int8-valued
    const float* wscale = (const float*)d_in[2];  // [1,1,4096]
    const float* bias   = (const float*)d_in[3];  // [4096]
    float* out = (float*)d_out;                   // [4,2048,4096]

    char* ws = (char*)d_ws;
    signed char* Aq = (signed char*)ws;                             // 32 MB
    signed char* Wq = (signed char*)(ws + (size_t)32 * 1024 * 1024);// 16 MB
    float* partials = (float*)(ws + (size_t)48 * 1024 * 1024);      // 2048 f
    float* scal     = partials + 2048;                              // 2 f
    int*   rowsum   = (int*)(scal + 16);                            // 4096 i
    float* outsc    = (float*)(rowsum + 4096);                      // 4096 f
    float* bias2    = outsc + 4096;                                 // 4096 f

    long n_x = (long)M_DIM * K_DIM;        // 33554432

    mmcw_kernel<<<2048, 256, 0, stream>>>(x, n_x / 4, partials, weight, Wq, rowsum);
    finalize_fold_kernel<<<1, 256, 0, stream>>>(partials, rowsum, wscale, bias,
                                                scal, outsc, bias2);
    quantize_kernel<<<2048, 256, 0, stream>>>(x, scal, (uint4*)Aq, n_x / 16);

    int lds_bytes = 131072;  // 2 bufs x (A 32KB + B 32KB)
    (void)hipFuncSetAttribute((const void*)gemm_kernel,
                              hipFuncAttributeMaxDynamicSharedMemorySize,
                              lds_bytes);
    dim3 grid((M_DIM / BM) * (N_DIM / BN));  // 32*16 = 512
    gemm_kernel<<<grid, 512, lds_bytes, stream>>>(Aq, Wq, outsc, bias2, out);
}

// Round 9
// 197.271 us; speedup vs baseline: 1.0661x; 1.0661x over previous
//
#include <hip/hip_runtime.h>
#include <hip/hip_bf16.h>
#include <stdint.h>

typedef __attribute__((ext_vector_type(4))) int i32x4;

#define K_DIM 4096
#define M_DIM 8192
#define N_DIM 4096

#define BM 256
#define BN 256
#define BKB 128                  // K-bytes (=128 i8) per K-tile
#define K_TILES (K_DIM / BKB)    // 32
#define GITERS (K_TILES / 2)     // 16 iterations, 2 K-tiles each

// ---------------------------------------------------------------- helpers
__device__ __forceinline__ void gload_lds16(const void* g, void* l) {
    __builtin_amdgcn_global_load_lds(
        (__attribute__((address_space(1))) void*)(void*)g,
        (__attribute__((address_space(3))) void*)(void*)l,
        16, 0, 0);
}

// ---------------------------------------------------------------- kernel 1: fused min/max partials + weight conv
// blocks 0..1023:  grid-stride min/max over x -> partials
// blocks 1024..2047: weight fp32 -> i8 + rowsum (4 rows/block, 1 wave/row)
__global__ void mmcw_kernel(const float* __restrict__ x, long n4,
                            float* __restrict__ partials,
                            const float* __restrict__ w,
                            signed char* __restrict__ Wq,
                            int* __restrict__ rowsum) {
    if (blockIdx.x < 1024) {
        const float4* x4 = (const float4*)x;
        float mn = 1e30f, mx = -1e30f;
        long stride = (long)1024 * blockDim.x;
        for (long i = (long)blockIdx.x * blockDim.x + threadIdx.x; i < n4; i += stride) {
            float4 v = x4[i];
            mn = fminf(mn, fminf(fminf(v.x, v.y), fminf(v.z, v.w)));
            mx = fmaxf(mx, fmaxf(fmaxf(v.x, v.y), fmaxf(v.z, v.w)));
        }
        #pragma unroll
        for (int off = 32; off; off >>= 1) {
            mn = fminf(mn, __shfl_down(mn, off));
            mx = fmaxf(mx, __shfl_down(mx, off));
        }
        __shared__ float smn[4], smx[4];
        int wid = threadIdx.x >> 6, lane = threadIdx.x & 63;
        if (lane == 0) { smn[wid] = mn; smx[wid] = mx; }
        __syncthreads();
        if (threadIdx.x == 0) {
            mn = fminf(fminf(smn[0], smn[1]), fminf(smn[2], smn[3]));
            mx = fmaxf(fmaxf(smx[0], smx[1]), fmaxf(smx[2], smx[3]));
            partials[blockIdx.x] = mn;
            partials[1024 + blockIdx.x] = mx;
        }
    } else {
        int row = (blockIdx.x - 1024) * 4 + (threadIdx.x >> 6);
        int lane = threadIdx.x & 63;
        const float4* src = (const float4*)(w + (long)row * K_DIM);  // 1024 float4/row
        uint4* dst = (uint4*)(Wq + (long)row * K_DIM);               // 256 uint4/row
        float s = 0.f;
        #pragma unroll
        for (int k = 0; k < 4; k++) {
            int u = k * 64 + lane;          // uint4 index 0..255
            unsigned wrd[4];
            #pragma unroll
            for (int j = 0; j < 4; j++) {
                float4 v = src[u * 4 + j];
                float e[4] = {v.x, v.y, v.z, v.w};
                unsigned word = 0;
                #pragma unroll
                for (int b = 0; b < 4; b++) {
                    int iv = (int)e[b];                  // exact: integer-valued fp32
                    s += e[b];
                    word |= ((unsigned)iv & 0xffu) << (8 * b);
                }
                wrd[j] = word;
            }
            uint4 o; o.x = wrd[0]; o.y = wrd[1]; o.z = wrd[2]; o.w = wrd[3];
            dst[u] = o;
        }
        #pragma unroll
        for (int off = 32; off; off >>= 1) s += __shfl_down(s, off);
        if (lane == 0) rowsum[row] = (int)s;             // exact: |sum| < 2^24
    }
}

// ---------------------------------------------------------------- kernel 2: quantize x -> i8 (self-reduces scale/zp)
__global__ void quantize_kernel(const float* __restrict__ x,
                                const float* __restrict__ partials,
                                uint4* __restrict__ q, long n16) {
    // block-local reduction of the 1024+1024 partials (bitwise-deterministic)
    float mn = 1e30f, mx = -1e30f;
    for (int i = threadIdx.x; i < 1024; i += 256) {
        mn = fminf(mn, partials[i]);
        mx = fmaxf(mx, partials[1024 + i]);
    }
    #pragma unroll
    for (int off = 32; off; off >>= 1) {
        mn = fminf(mn, __shfl_down(mn, off));
        mx = fmaxf(mx, __shfl_down(mx, off));
    }
    __shared__ float smn[4], smx[4];
    int wid = threadIdx.x >> 6, lane = threadIdx.x & 63;
    if (lane == 0) { smn[wid] = mn; smx[wid] = mx; }
    __syncthreads();
    mn = fminf(fminf(smn[0], smn[1]), fminf(smn[2], smn[3]));
    mx = fmaxf(fmaxf(smx[0], smx[1]), fmaxf(smx[2], smx[3]));
    float scale = (mx - mn) / 255.0f;
    float zp = rintf(-128.0f - mn / scale);
    zp = fminf(fmaxf(zp, -128.0f), 127.0f);

    long stride = (long)gridDim.x * blockDim.x;
    for (long i = (long)blockIdx.x * blockDim.x + threadIdx.x; i < n16; i += stride) {
        const float4* xp = (const float4*)x + i * 4;
        unsigned wrd[4];
        #pragma unroll
        for (int w = 0; w < 4; w++) {
            float4 v = xp[w];
            float e[4] = {v.x, v.y, v.z, v.w};
            unsigned word = 0;
            #pragma unroll
            for (int j = 0; j < 4; j++) {
                float qf = rintf(e[j] / scale + zp);          // matches reference rounding
                qf = fminf(fmaxf(qf, -128.0f), 127.0f);
                int iq = (int)qf;
                word |= ((unsigned)iq & 0xffu) << (8 * j);
            }
            wrd[w] = word;
        }
        uint4 o; o.x = wrd[0]; o.y = wrd[1]; o.z = wrd[2]; o.w = wrd[3];
        q[i] = o;
    }
}

// ---------------------------------------------------------------- kernel 3: i8 GEMM, 8-phase (round-5/7 verified)
// 256x256 tile, K-tile = 128 B (128 i8), 512 threads (8 waves 2Mx4N),
// 2 K-tile LDS buffers (128 KiB), 8 phases/iter, counted vmcnt(6), setprio,
// 16B-slot XOR swizzle (inverse-permuted global source + swizzled ds_read).
// mfma_i32_16x16x64_i8; A/B frags use identical lane->byte maps (k-perm
// invariant); C/D: col=lane&15, row=(lane>>4)*4+reg.
// Epilogue folds dequant coefficients in-kernel: scale/zp from partials
// (after the main loop, vmcnt ledger closed), os/bias2 per column.
__global__ __launch_bounds__(512, 2) void gemm_kernel(
    const signed char* __restrict__ A,   // [8192][4096] i8 (q, zp NOT subtracted)
    const signed char* __restrict__ W,   // [4096][4096] i8
    const float* __restrict__ partials,
    const int* __restrict__ rowsum,
    const float* __restrict__ wscale,
    const float* __restrict__ bias,
    float* __restrict__ C) {
    extern __shared__ char lds[];
    char* As = lds;            // 2 bufs x 32768 B (2 units x 128 rows x 128 B)
    char* Bs = lds + 65536;

    // XCD-aware swizzle (nwg = 512, divisible by 8)
    int nwg = gridDim.x;
    int cpx = nwg >> 3;
    int bid = blockIdx.x;
    int wg = (bid & 7) * cpx + (bid >> 3);
    int tm = wg >> 4;   // 32 M-tiles
    int tn = wg & 15;   // 16 N-tiles
    int m0 = tm * BM, n0 = tn * BN;

    int t = threadIdx.x;
    int wid = t >> 6, lane = t & 63;
    int wr = wid >> 2, wc = wid & 3;      // 2 x 4 wave grid
    int lr = lane & 15, lk = lane >> 4;
    int ksw0 = (lk ^ (lr & 7)) * 16;          // byte offset, khalf0 (k 0..63)
    int ksw1 = ((4 + lk) ^ (lr & 7)) * 16;    // khalf1 (k 64..127)

    // staging source geometry (byte units)
    int R0 = t >> 3;                              // 0..63
    int csw = ((t & 7) ^ ((t >> 3) & 7)) * 16;    // inverse-swizzled source col
    const signed char* aSrc = A + (long)(m0 + R0) * K_DIM + csw;
    const signed char* bSrc = W + (long)(n0 + ((R0 >> 5) << 6) + (R0 & 31)) * K_DIM + csw;
    int ldd = t * 16;                             // lds dest bytes

#define STAGE_A(BUF, UN, KT) do { \
    const signed char* _s = aSrc + (long)(UN) * 64 * K_DIM + (long)(KT) * BKB; \
    char* _d = As + (BUF) * 32768 + (UN) * 16384 + ldd; \
    gload_lds16(_s, _d); \
    gload_lds16(_s + (long)128 * K_DIM, _d + 8192); } while (0)

#define STAGE_B(BUF, UN, KT) do { \
    const signed char* _s = bSrc + (long)(UN) * 32 * K_DIM + (long)(KT) * BKB; \
    char* _d = Bs + (BUF) * 32768 + (UN) * 16384 + ldd; \
    gload_lds16(_s, _d); \
    gload_lds16(_s + (long)128 * K_DIM, _d + 8192); } while (0)

#define READ_A(BUF, MH) do { \
    const char* _p = As + (BUF) * 32768 + (MH) * 16384 + (wr * 64 + lr) * 128; \
    _Pragma("unroll") \
    for (int _mm = 0; _mm < 4; ++_mm) { \
        a[_mm * 2]     = *(const i32x4*)(_p + _mm * 2048 + ksw0); \
        a[_mm * 2 + 1] = *(const i32x4*)(_p + _mm * 2048 + ksw1); } } while (0)

#define READ_B(BUF, NH, BR) do { \
    const char* _p = Bs + (BUF) * 32768 + (NH) * 16384 + (wc * 32 + lr) * 128; \
    _Pragma("unroll") \
    for (int _nn = 0; _nn < 2; ++_nn) { \
        BR[_nn * 2]     = *(const i32x4*)(_p + _nn * 2048 + ksw0); \
        BR[_nn * 2 + 1] = *(const i32x4*)(_p + _nn * 2048 + ksw1); } } while (0)

#define MFMA_QUAD(MH, NH, BR) do { \
    _Pragma("unroll") \
    for (int _mm = 0; _mm < 4; ++_mm) \
    _Pragma("unroll") \
    for (int _nn = 0; _nn < 2; ++_nn) { \
        acc[(MH) * 4 + _mm][(NH) * 2 + _nn] = __builtin_amdgcn_mfma_i32_16x16x64_i8( \
            a[_mm * 2], BR[_nn * 2], acc[(MH) * 4 + _mm][(NH) * 2 + _nn], 0, 0, 0); \
        acc[(MH) * 4 + _mm][(NH) * 2 + _nn] = __builtin_amdgcn_mfma_i32_16x16x64_i8( \
            a[_mm * 2 + 1], BR[_nn * 2 + 1], acc[(MH) * 4 + _mm][(NH) * 2 + _nn], 0, 0, 0); } } while (0)

#define BAR()   asm volatile("s_barrier" ::: "memory")
#define LGKM0() asm volatile("s_waitcnt lgkmcnt(0)" ::: "memory")
#define LGKM8() asm volatile("s_waitcnt lgkmcnt(8)" ::: "memory")
#define VM6()   asm volatile("s_waitcnt vmcnt(6)" ::: "memory")
#define VM0()   asm volatile("s_waitcnt vmcnt(0)" ::: "memory")
#define PRIO1() __builtin_amdgcn_s_setprio(1)
#define PRIO0() __builtin_amdgcn_s_setprio(0)

    i32x4 acc[8][4];
    #pragma unroll
    for (int i = 0; i < 8; i++)
        #pragma unroll
        for (int j = 0; j < 4; j++)
            acc[i][j] = (i32x4){0, 0, 0, 0};

    i32x4 a[8], b0[4], b1[4];

    // ---- prologue: tile0 fully -> buf0, tile1 units u0A,u0B,u1B -> buf1
    STAGE_A(0, 0, 0); STAGE_B(0, 0, 0); STAGE_B(0, 1, 0); STAGE_A(0, 1, 0);
    STAGE_A(1, 0, 1); STAGE_B(1, 0, 1); STAGE_B(1, 1, 1);
    VM6();   // 14 issued, wait 8 oldest = all of tile 0
    BAR();

    for (int it = 0; it < GITERS; ++it) {
        int t1 = 2 * it + 1;
        int tn0 = 2 * it + 2, tn1 = 2 * it + 3;
        bool st = (it < GITERS - 1);

        // ---- P1: quadrant (0,0) of even tile (buf0)
        READ_A(0, 0);
        READ_B(0, 0, b0);
        STAGE_A(1, 1, t1);
        LGKM8();
        BAR(); LGKM0();
        PRIO1(); MFMA_QUAD(0, 0, b0); PRIO0();
        BAR();

        // ---- P2: (0,1)
        READ_B(0, 1, b1);
        if (st) STAGE_A(0, 0, tn0);
        BAR(); LGKM0();
        PRIO1(); MFMA_QUAD(0, 1, b1); PRIO0();
        BAR();

        // ---- P3: (1,1)
        READ_A(0, 1);
        if (st) STAGE_B(0, 0, tn0);
        BAR(); LGKM0();
        PRIO1(); MFMA_QUAD(1, 1, b1); PRIO0();
        BAR();

        // ---- P4: (1,0)  [vmcnt point]
        if (st) { STAGE_B(0, 1, tn0); VM6(); } else { VM0(); }
        BAR();
        PRIO1(); MFMA_QUAD(1, 0, b0); PRIO0();
        BAR();

        // ---- P5: quadrant (0,0) of odd tile (buf1)
        READ_A(1, 0);
        READ_B(1, 0, b0);
        if (st) STAGE_A(0, 1, tn0);
        LGKM8();
        BAR(); LGKM0();
        PRIO1(); MFMA_QUAD(0, 0, b0); PRIO0();
        BAR();

        // ---- P6: (0,1)
        READ_B(1, 1, b1);
        if (st) STAGE_A(1, 0, tn1);
        BAR(); LGKM0();
        PRIO1(); MFMA_QUAD(0, 1, b1); PRIO0();
        BAR();

        // ---- P7: (1,1)
        READ_A(1, 1);
        if (st) STAGE_B(1, 0, tn1);
        BAR(); LGKM0();
        PRIO1(); MFMA_QUAD(1, 1, b1); PRIO0();
        BAR();

        // ---- P8: (1,0)  [vmcnt point]
        if (st) { STAGE_B(1, 1, tn1); VM6(); }
        BAR();
        PRIO1(); MFMA_QUAD(1, 0, b0); PRIO0();
        BAR();
    }

    // ---- epilogue: fold dequant coefficients in-kernel.
    // scale/zp reduction (bitwise-identical math to quantize_kernel).
    float mn = 1e30f, mx = -1e30f;
    for (int i = t; i < 1024; i += 512) {
        mn = fminf(mn, partials[i]);
        mx = fmaxf(mx, partials[1024 + i]);
    }
    #pragma unroll
    for (int off = 32; off; off >>= 1) {
        mn = fminf(mn, __shfl_down(mn, off));
        mx = fmaxf(mx, __shfl_down(mx, off));
    }
    float* red = (float*)lds;   // LDS free after final barrier
    __syncthreads();
    if (lane == 0) { red[wid] = mn; red[8 + wid] = mx; }
    __syncthreads();
    mn = red[0]; mx = red[8];
    #pragma unroll
    for (int i = 1; i < 8; i++) {
        mn = fminf(mn, red[i]);
        mx = fmaxf(mx, red[8 + i]);
    }
    float scale = (mx - mn) / 255.0f;
    float zp = rintf(-128.0f - mn / scale);
    zp = fminf(fmaxf(zp, -128.0f), 127.0f);

    // C/D layout col = lane&15, row = (lane>>4)*4 + reg
    #pragma unroll
    for (int j = 0; j < 4; j++) {
        int col = n0 + wc * 64 + j * 16 + lr;
        float os = scale * wscale[col];
        float bs = bias[col] - zp * (float)rowsum[col] * os;
        #pragma unroll
        for (int i = 0; i < 8; i++) {
            int rbase = m0 + wr * 128 + i * 16 + lk * 4;
            #pragma unroll
            for (int r = 0; r < 4; r++) {
                C[(long)(rbase + r) * N_DIM + col] = (float)acc[i][j][r] * os + bs;
            }
        }
    }
#undef STAGE_A
#undef STAGE_B
#undef READ_A
#undef READ_B
#undef MFMA_QUAD
}

// ---------------------------------------------------------------- launch
extern "C" void kernel_launch(void* const* d_in, const int* in_sizes, int n_in,
                              void* d_out, int out_size, void* d_ws, size_t ws_size,
                              hipStream_t stream) {
    const float* x      = (const float*)d_in[0];  // [4,2048,4096]
    const float* weight = (const float*)d_in[1];  // [4096,4096] int8-valued
    const float* wscale = (const float*)d_in[2];  // [1,1,4096]
    const float* bias   = (const float*)d_in[3];  // [4096]
    float* out = (float*)d_out;                   // [4,2048,4096]

    char* ws = (char*)d_ws;
    signed char* Aq = (signed char*)ws;                             // 32 MB
    signed char* Wq = (signed char*)(ws + (size_t)32 * 1024 * 1024);// 16 MB
    float* partials = (float*)(ws + (size_t)48 * 1024 * 1024);      // 2048 f
    int*   rowsum   = (int*)(partials + 2048);                      // 4096 i

    long n_x = (long)M_DIM * K_DIM;        // 33554432

    mmcw_kernel<<<2048, 256, 0, stream>>>(x, n_x / 4, partials, weight, Wq, rowsum);
    quantize_kernel<<<2048, 256, 0, stream>>>(x, partials, (uint4*)Aq, n_x / 16);

    int lds_bytes = 131072;  // 2 bufs x (A 32KB + B 32KB)
    (void)hipFuncSetAttribute((const void*)gemm_kernel,
                              hipFuncAttributeMaxDynamicSharedMemorySize,
                              lds_bytes);
    dim3 grid((M_DIM / BM) * (N_DIM / BN));  // 32*16 = 512
    gemm_kernel<<<grid, 512, lds_bytes, stream>>>(Aq, Wq, partials, rowsum,
                                                  wscale, bias, out);
}